// Round 3
// baseline (1825.481 us; speedup 1.0000x reference)
//
#include <hip/hip_runtime.h>
#include <hip/hip_bf16.h>

#define N_NODES 25000
#define N_EDGES 250000
#define F_IN 32
#define F_OUT 32
#define ED 6
#define H1 64
#define H2 128
#define KC 8           // h2 k-chunk kept in registers
#define THREADS 256

// CAS-loop float atomic add: correct on any memory type regardless of
// -munsafe-fp-atomics.
__device__ __forceinline__ void atomic_add_f32(float* p, float v) {
    unsigned int* up = (unsigned int*)p;
    unsigned int assumed, old = *up;
    do {
        assumed = old;
        old = atomicCAS(up, assumed, __float_as_uint(__uint_as_float(assumed) + v));
    } while (old != assumed);
}

__global__ __launch_bounds__(256) void ecc_zero(float* __restrict__ ws, int n) {
    int i = blockIdx.x * 256 + threadIdx.x;
    if (i < n) ws[i] = 0.f;
}

// One thread per edge. Weight reads are wave-uniform -> scalar loads.
// Fuses: fnet MLP (6->64->128->1024) + einsum('eoi,ei->eo') + atomic scatter.
__global__ __launch_bounds__(THREADS) void ecc_edge(
    const float* __restrict__ x,   const float* __restrict__ ea,
    const float* __restrict__ W1,  const float* __restrict__ b1,
    const float* __restrict__ W2,  const float* __restrict__ b2,
    const float* __restrict__ W3,  const float* __restrict__ b3,
    const int* __restrict__ src,   const int* __restrict__ dst,
    float* __restrict__ agg, float* __restrict__ deg)
{
    const int e = blockIdx.x * THREADS + threadIdx.x;
    if (e >= N_EDGES) return;

    // ---- gather source-node features into registers ----
    float xs[F_IN];
    {
        const int s = src[e];
        const float4* xv = (const float4*)(x + (long)s * F_IN);
        #pragma unroll
        for (int q = 0; q < F_IN / 4; ++q) {
            float4 v = xv[q];
            xs[q*4+0] = v.x; xs[q*4+1] = v.y; xs[q*4+2] = v.z; xs[q*4+3] = v.w;
        }
    }

    // ---- edge attributes ----
    float a[ED];
    #pragma unroll
    for (int c = 0; c < ED; ++c) a[c] = ea[(long)e * ED + c];

    // ---- layer 1: h1 = relu(ea @ W1^T + b1), kept in registers ----
    float h1[H1];
    #pragma unroll
    for (int o = 0; o < H1; ++o) {
        float acc = b1[o];
        #pragma unroll
        for (int c = 0; c < ED; ++c) acc = fmaf(W1[o*ED + c], a[c], acc);
        h1[o] = fmaxf(acc, 0.f);
    }

    float msg[F_OUT];
    #pragma unroll
    for (int o = 0; o < F_OUT; ++o) msg[o] = 0.f;

    // ---- layers 2+3 fused, chunked over the H2 axis ----
    // theta[o][i] = dot(W3[o*32+i, :], h2); msg[o] = sum_i theta[o][i]*xs[i]
    // reorder: tacc[k] = sum_i W3[o*32+i][kc+k]*xs[i]; msg[o] += sum_k h2c[k]*tacc[k]
    #pragma unroll 1
    for (int kc = 0; kc < H2; kc += KC) {
        float h2c[KC];
        #pragma unroll
        for (int k = 0; k < KC; ++k) {
            const int r = kc + k;
            float acc = b2[r];
            const float* w = W2 + r * H1;
            #pragma unroll
            for (int c = 0; c < H1; ++c) acc = fmaf(w[c], h1[c], acc);
            h2c[k] = fmaxf(acc, 0.f);
        }
        #pragma unroll 1
        for (int o = 0; o < F_OUT; ++o) {
            float tacc[KC];
            #pragma unroll
            for (int k = 0; k < KC; ++k) tacc[k] = 0.f;
            #pragma unroll
            for (int i = 0; i < F_IN; ++i) {
                const float* w = W3 + (long)(o * F_IN + i) * H2 + kc;
                const float xi = xs[i];
                #pragma unroll
                for (int k = 0; k < KC; ++k) tacc[k] = fmaf(w[k], xi, tacc[k]);
            }
            float m = 0.f;
            #pragma unroll
            for (int k = 0; k < KC; ++k) m = fmaf(h2c[k], tacc[k], m);
            msg[o] += m;
        }
    }

    // ---- b3 contribution: msg[o] += sum_i b3[o*32+i]*xs[i] ----
    #pragma unroll 1
    for (int o = 0; o < F_OUT; ++o) {
        float bacc = 0.f;
        #pragma unroll
        for (int i = 0; i < F_IN; ++i) bacc = fmaf(b3[o*F_IN + i], xs[i], bacc);
        msg[o] += bacc;
    }

    // ---- scatter-sum + degree count ----
    const int d = dst[e];
    atomic_add_f32(&deg[d], 1.f);
    float* ag = agg + (long)d * F_OUT;
    #pragma unroll 1
    for (int o = 0; o < F_OUT; ++o) atomic_add_f32(&ag[o], msg[o]);
}

// Output is FLOAT32 (the reference's output dtype) — NOT bf16.
__global__ __launch_bounds__(256) void ecc_finalize(
    const float* __restrict__ agg, const float* __restrict__ deg,
    float* __restrict__ out)
{
    const int i = blockIdx.x * 256 + threadIdx.x;
    if (i >= N_NODES * F_OUT) return;
    const int n = i >> 5;   // / F_OUT
    const float d = fmaxf(deg[n], 1.f);
    out[i] = fmaxf(agg[i] / d, 0.f);
}

extern "C" void kernel_launch(void* const* d_in, const int* in_sizes, int n_in,
                              void* d_out, int out_size, void* d_ws, size_t ws_size,
                              hipStream_t stream) {
    const float* x   = (const float*)d_in[0];
    const float* ea  = (const float*)d_in[1];
    const float* W1  = (const float*)d_in[2];
    const float* b1  = (const float*)d_in[3];
    const float* W2  = (const float*)d_in[4];
    const float* b2  = (const float*)d_in[5];
    const float* W3  = (const float*)d_in[6];
    const float* b3  = (const float*)d_in[7];
    const int*   src = (const int*)d_in[8];
    const int*   dst = (const int*)d_in[9];
    float* out = (float*)d_out;

    float* agg = (float*)d_ws;                       // [N_NODES, F_OUT]
    float* deg = agg + (long)N_NODES * F_OUT;        // [N_NODES]
    const int nz = N_NODES * F_OUT + N_NODES;

    // zero accumulators every call (harness does not re-poison between replays)
    ecc_zero<<<(nz + 255) / 256, 256, 0, stream>>>((float*)d_ws, nz);

    const int nblk = (N_EDGES + THREADS - 1) / THREADS;
    ecc_edge<<<nblk, THREADS, 0, stream>>>(x, ea, W1, b1, W2, b2, W3, b3, src, dst, agg, deg);

    const int n2 = (N_NODES * F_OUT + 255) / 256;
    ecc_finalize<<<n2, 256, 0, stream>>>(agg, deg, out);
}

// Round 4
// 399.471 us; speedup vs baseline: 4.5697x; 4.5697x over previous
//
#include <hip/hip_runtime.h>

#define N_NODES 25000
#define N_EDGES 250000
#define F_IN 32
#define F_OUT 32
#define ED 6
#define H1 64
#define H2 128
#define NBLK 977                 // ceil(250000/256)
#define E_PAD (NBLK*256)
#define K_TOT 4160               // 4096 (h2 x xs) + 32 (b3 x xs) + 32 zero pad
#define CK 256                   // K-chunk (k' values) for chunks 0..15
#define CK_LAST 64               // chunk 16: b3 (32) + pad (32)
#define W3S_USHORTS (32*K_TOT)   // 133120

typedef float f32x4 __attribute__((ext_vector_type(4)));
typedef short s16x8 __attribute__((ext_vector_type(8)));

__device__ __forceinline__ unsigned short f2bf(float f) {
    union { float f; unsigned u; } v; v.f = f;
    return (unsigned short)((v.u + 0x7FFF + ((v.u >> 16) & 1)) >> 16);  // RNE
}
__device__ __forceinline__ float bf2f(unsigned short h) {
    union { unsigned u; float f; } v; v.u = ((unsigned)h) << 16;
    return v.f;
}

__global__ __launch_bounds__(256) void ecc_zero(float* __restrict__ ws, int n) {
    int i = blockIdx.x * 256 + threadIdx.x;
    if (i < n) ws[i] = 0.f;
}

// Repack W3 (+b3) into bf16 B-matrix [32 rows(o)][K_TOT cols(k')], chunked
// (chunks 0..15: CK k' each; chunk 16: CK_LAST), bytes pre-XOR-swizzled with
// ((o&7)<<4) so GEMM-side ds_read_b128 B-fragments are bank-conflict-free.
// k' = k*32 + i for k<128; k'=4096+i is the b3 row-block; k'>=4128 zero pad.
__global__ __launch_bounds__(256) void ecc_w3s(
    const float* __restrict__ W3, const float* __restrict__ b3,
    unsigned short* __restrict__ w3s)
{
    int idx = blockIdx.x * 256 + threadIdx.x;
    if (idx >= W3S_USHORTS) return;
    int o = idx / K_TOT, kp = idx % K_TOT;
    float v = 0.f;
    if (kp < 4096) { int k = kp >> 5, i = kp & 31; v = W3[(o * 32 + i) * 128 + k]; }
    else if (kp < 4128) { int i = kp - 4096; v = b3[o * 32 + i]; }
    int c, kl, ck;
    if (kp < 4096) { c = kp / CK; kl = kp % CK; ck = CK; }
    else { c = 16; kl = kp - 4096; ck = CK_LAST; }
    int off = o * (ck * 2) + kl * 2;          // byte offset within chunk
    off ^= ((o & 7) << 4);                    // T2 swizzle
    int cbase = c * (32 * CK);                // ushort base (chunks 0..15 are 8192 ushorts)
    w3s[cbase + off / 2] = f2bf(v);
}

// Fused: per-edge MLP (VALU, static regs) -> h2 tile in LDS -> on-the-fly
// rank-1 A-operand MFMA GEMM [256e, 4128] x [4128, 32o] -> atomic scatter.
__global__ __launch_bounds__(256) void ecc_main(
    const float* __restrict__ x,   const float* __restrict__ ea,
    const float* __restrict__ W1,  const float* __restrict__ b1,
    const float* __restrict__ W2,  const float* __restrict__ b2,
    const unsigned short* __restrict__ w3s,
    const int* __restrict__ src,   const int* __restrict__ dst,
    float* __restrict__ agg, float* __restrict__ deg)
{
    __shared__ unsigned short h2s[H2][256];     // 64KB, transposed [k][e_local], bf16
    __shared__ unsigned short wbuf[32 * CK];    // 16KB B-chunk buffer

    const int t = threadIdx.x;
    const int tile = blockIdx.x * 256;
    const int e = tile + t;
    const bool ev = (e < N_EDGES);

    if (ev) atomicAdd(&deg[dst[e]], 1.f);

    // ---------------- phase 0: MLP -> h2s (all arrays statically indexed) ----
    {
        float a[ED];
        #pragma unroll
        for (int c = 0; c < ED; ++c) a[c] = ev ? ea[(long)e * ED + c] : 0.f;

        float h1[H1];
        #pragma unroll
        for (int o = 0; o < H1; ++o) {
            float acc = b1[o];
            #pragma unroll
            for (int c = 0; c < ED; ++c) acc = fmaf(W1[o * ED + c], a[c], acc);
            h1[o] = fmaxf(acc, 0.f);
        }
        #pragma unroll 1
        for (int kc = 0; kc < H2 / 8; ++kc) {
            float h2c[8];
            #pragma unroll
            for (int k = 0; k < 8; ++k) {
                const int r = kc * 8 + k;
                float acc = b2[r];
                const float* w = W2 + r * H1;
                #pragma unroll
                for (int c = 0; c < H1; ++c) acc = fmaf(w[c], h1[c], acc);
                h2c[k] = fmaxf(acc, 0.f);
            }
            #pragma unroll
            for (int k = 0; k < 8; ++k)
                h2s[kc * 8 + k][t] = ev ? f2bf(h2c[k]) : (unsigned short)0;
        }
    }

    // ---------------- xs fragments (per lane, per m-tile): 8 fp32 -------------
    const int w  = t >> 6;        // wave id: owns m-tiles 4w..4w+3
    const int l  = t & 63;
    const int lr = l & 15;        // A-row / B-col / C-col index
    const int kg = l >> 4;        // k-group (8 consecutive k each)

    float xsf[4][8];
    #pragma unroll
    for (int mt = 0; mt < 4; ++mt) {
        const int er = tile + w * 64 + mt * 16 + lr;
        if (er < N_EDGES) {
            const float4* xp = (const float4*)(x + (long)src[er] * F_IN + kg * 8);
            float4 v0 = xp[0], v1 = xp[1];
            xsf[mt][0] = v0.x; xsf[mt][1] = v0.y; xsf[mt][2] = v0.z; xsf[mt][3] = v0.w;
            xsf[mt][4] = v1.x; xsf[mt][5] = v1.y; xsf[mt][6] = v1.z; xsf[mt][7] = v1.w;
        } else {
            #pragma unroll
            for (int j = 0; j < 8; ++j) xsf[mt][j] = 0.f;
        }
    }

    f32x4 acc[4][2];
    #pragma unroll
    for (int mt = 0; mt < 4; ++mt)
        #pragma unroll
        for (int nt = 0; nt < 2; ++nt)
            acc[mt][nt] = (f32x4){0.f, 0.f, 0.f, 0.f};

    // ---------------- K loop over 17 B-chunks --------------------------------
    #pragma unroll 1
    for (int c = 0; c < 17; ++c) {
        const int ck  = (c < 16) ? CK : CK_LAST;
        const int nks = ck / 32;                  // 8 or 2 K-steps
        if (c > 0) __syncthreads();               // all waves done with wbuf
        {   // stage chunk (linear, both sides pre-swizzled identically)
            const uint4* gs = (const uint4*)(w3s + c * (32 * CK));
            uint4* ld = (uint4*)wbuf;
            const int nv = (ck * 64) / 16;        // 1024 or 256 16B vectors
            for (int i = t; i < nv; i += 256) ld[i] = gs[i];
        }
        __syncthreads();                          // chunk ready (c==0: also h2s)

        #pragma unroll 1
        for (int kk = 0; kk < nks; ++kk) {
            const int kglob = (c < 16) ? c * 8 + kk : 128 + kk;
            // B fragments: 2 n-tiles, swizzled ds_read_b128
            s16x8 bfrag[2];
            #pragma unroll
            for (int nt = 0; nt < 2; ++nt) {
                const int o = nt * 16 + lr;
                int off = o * (ck * 2) + (kk * 32 + kg * 8) * 2;
                off ^= ((o & 7) << 4);
                bfrag[nt] = *(const s16x8*)((const char*)wbuf + off);
            }
            // A fragments: u[row, i] = h2[row, kglob] * xs[row, i]
            #pragma unroll
            for (int mt = 0; mt < 4; ++mt) {
                float hs;
                if (kglob < 128)      hs = bf2f(h2s[kglob][w * 64 + mt * 16 + lr]);
                else if (kglob == 128) hs = 1.f;   // b3 block: A = xs
                else                   hs = 0.f;   // zero pad
                s16x8 af;
                #pragma unroll
                for (int j = 0; j < 8; ++j) af[j] = (short)f2bf(hs * xsf[mt][j]);
                #pragma unroll
                for (int nt = 0; nt < 2; ++nt)
                    acc[mt][nt] = __builtin_amdgcn_mfma_f32_16x16x32_bf16(
                        af, bfrag[nt], acc[mt][nt], 0, 0, 0);
            }
        }
    }

    // ---------------- epilogue: atomic scatter -------------------------------
    // C layout (m89-verified): col = lane&15 (o), row = (lane>>4)*4 + reg (edge)
    #pragma unroll
    for (int mt = 0; mt < 4; ++mt) {
        #pragma unroll
        for (int r = 0; r < 4; ++r) {
            const int e2 = tile + w * 64 + mt * 16 + kg * 4 + r;
            if (e2 < N_EDGES) {
                const int d = dst[e2];
                #pragma unroll
                for (int nt = 0; nt < 2; ++nt)
                    atomicAdd(&agg[(long)d * F_OUT + nt * 16 + lr], acc[mt][nt][r]);
            }
        }
    }
}

__global__ __launch_bounds__(256) void ecc_finalize(
    const float* __restrict__ agg, const float* __restrict__ deg,
    float* __restrict__ out)
{
    const int i = blockIdx.x * 256 + threadIdx.x;
    if (i >= N_NODES * F_OUT) return;
    const int n = i >> 5;
    const float d = fmaxf(deg[n], 1.f);
    out[i] = fmaxf(agg[i] / d, 0.f);
}

extern "C" void kernel_launch(void* const* d_in, const int* in_sizes, int n_in,
                              void* d_out, int out_size, void* d_ws, size_t ws_size,
                              hipStream_t stream) {
    const float* x   = (const float*)d_in[0];
    const float* ea  = (const float*)d_in[1];
    const float* W1  = (const float*)d_in[2];
    const float* b1  = (const float*)d_in[3];
    const float* W2  = (const float*)d_in[4];
    const float* b2  = (const float*)d_in[5];
    const float* W3  = (const float*)d_in[6];
    const float* b3  = (const float*)d_in[7];
    const int*   src = (const int*)d_in[8];
    const int*   dst = (const int*)d_in[9];
    float* out = (float*)d_out;

    float* agg = (float*)d_ws;                                // [N_NODES, F_OUT]
    float* deg = agg + (long)N_NODES * F_OUT;                 // [N_NODES]
    unsigned short* w3s = (unsigned short*)(deg + N_NODES);   // [W3S_USHORTS]

    const int nz = N_NODES * F_OUT + N_NODES;
    ecc_zero<<<(nz + 255) / 256, 256, 0, stream>>>((float*)d_ws, nz);
    ecc_w3s<<<(W3S_USHORTS + 255) / 256, 256, 0, stream>>>(W3, b3, w3s);
    ecc_main<<<NBLK, 256, 0, stream>>>(x, ea, W1, b1, W2, b2, w3s, src, dst, agg, deg);
    const int n2 = (N_NODES * F_OUT + 255) / 256;
    ecc_finalize<<<n2, 256, 0, stream>>>(agg, deg, out);
}

// Round 5
// 232.094 us; speedup vs baseline: 7.8653x; 1.7212x over previous
//
#include <hip/hip_runtime.h>

#define N_NODES 25000
#define N_EDGES 250000
#define F_IN 32
#define F_OUT 32
#define ED 6
#define H1 64
#define H2 128
#define NBLK 977                 // ceil(250000/256)
#define K_TOT 4160               // ushorts per o-row: 4096 (h2*xs) + 32 (b3) + 32 pad
#define W3S_USHORTS (32*K_TOT)   // 133120 = 266KB, L2-resident

typedef float f32x4 __attribute__((ext_vector_type(4)));
typedef short s16x8 __attribute__((ext_vector_type(8)));
typedef unsigned int u32x4 __attribute__((ext_vector_type(4)));

union ABu { u32x4 u; s16x8 s; };

// HW packed f32->bf16 (RNE), S0 -> low half, S1 -> high half (T12 recipe).
__device__ __forceinline__ unsigned cvt_pk_bf16(float lo, float hi) {
    unsigned r;
    asm("v_cvt_pk_bf16_f32 %0, %1, %2" : "=v"(r) : "v"(lo), "v"(hi));
    return r;
}
__device__ __forceinline__ unsigned short f2bf(float f) {   // cold paths only
    union { float f; unsigned u; } v; v.f = f;
    return (unsigned short)((v.u + 0x7FFF + ((v.u >> 16) & 1)) >> 16);
}
__device__ __forceinline__ float bf2f(unsigned short h) {
    union { unsigned u; float f; } v; v.u = ((unsigned)h) << 16;
    return v.f;
}

__global__ __launch_bounds__(256) void ecc_zero(float* __restrict__ ws, int n) {
    int i = blockIdx.x * 256 + threadIdx.x;
    if (i < n) ws[i] = 0.f;
}

// Repack W3 (+b3) -> bf16 B matrix, row-major [o=32][kp=K_TOT].
// kp = k*32+i (k<128); kp = 4096+i is the b3 block; kp >= 4128 zero pad.
__global__ __launch_bounds__(256) void ecc_w3s(
    const float* __restrict__ W3, const float* __restrict__ b3,
    unsigned short* __restrict__ w3s)
{
    int idx = blockIdx.x * 256 + threadIdx.x;
    if (idx >= W3S_USHORTS) return;
    int o = idx / K_TOT, kp = idx % K_TOT;
    float v = 0.f;
    if (kp < 4096)      { int k = kp >> 5, i = kp & 31; v = W3[(o * 32 + i) * 128 + k]; }
    else if (kp < 4128) { v = b3[o * 32 + (kp - 4096)]; }
    w3s[idx] = f2bf(v);
}

// Fused: per-edge MLP (VALU) -> h2 tile in LDS (row-major, XOR-swizzled) ->
// barrier-free MFMA K-loop with B-fragments loaded straight from L2-resident
// w3s and A built on the fly via v_cvt_pk_bf16_f32 -> atomic scatter.
__global__ __launch_bounds__(256) void ecc_main(
    const float* __restrict__ x,   const float* __restrict__ ea,
    const float* __restrict__ W1,  const float* __restrict__ b1,
    const float* __restrict__ W2,  const float* __restrict__ b2,
    const unsigned short* __restrict__ w3s,
    const int* __restrict__ src,   const int* __restrict__ dst,
    float* __restrict__ agg, float* __restrict__ deg)
{
    __shared__ unsigned short h2s[256 * H2];   // 64KB, [e][k] bf16, byte^((e&7)<<4)

    const int t = threadIdx.x;
    const int tile = blockIdx.x * 256;
    const int e = tile + t;
    const bool ev = (e < N_EDGES);

    if (ev) atomicAdd(&deg[dst[e]], 1.f);

    // ---------------- phase 0: MLP -> h2s ------------------------------------
    {
        float a[ED];
        #pragma unroll
        for (int c = 0; c < ED; ++c) a[c] = ev ? ea[(long)e * ED + c] : 0.f;

        float h1[H1];
        #pragma unroll
        for (int o = 0; o < H1; ++o) {
            float acc = b1[o];
            #pragma unroll
            for (int c = 0; c < ED; ++c) acc = fmaf(W1[o * ED + c], a[c], acc);
            h1[o] = fmaxf(acc, 0.f);
        }
        #pragma unroll 1
        for (int kc = 0; kc < H2 / 8; ++kc) {
            float h2c[8];
            #pragma unroll
            for (int k = 0; k < 8; ++k) {
                const int r = kc * 8 + k;
                float acc = b2[r];
                const float* w = W2 + r * H1;
                #pragma unroll
                for (int c = 0; c < H1; ++c) acc = fmaf(w[c], h1[c], acc);
                h2c[k] = fmaxf(acc, 0.f);
            }
            u32x4 pk;
            #pragma unroll
            for (int j = 0; j < 4; ++j) pk[j] = cvt_pk_bf16(h2c[2*j], h2c[2*j+1]);
            const int boff = (t * 256 + kc * 16) ^ ((t & 7) << 4);
            *(u32x4*)((char*)h2s + boff) = pk;
        }
    }

    // ---------------- per-lane xs (fp32) -------------------------------------
    const int w  = t >> 6;        // wave: owns edge rows w*64 .. w*64+63
    const int l  = t & 63;
    const int lr = l & 15;        // A-row / B-col / C-col
    const int kg = l >> 4;        // 8-wide k-group

    float xsf[4][8];
    #pragma unroll
    for (int mt = 0; mt < 4; ++mt) {
        const int er = tile + w * 64 + mt * 16 + lr;
        if (er < N_EDGES) {
            const float4* xp = (const float4*)(x + (long)src[er] * F_IN + kg * 8);
            float4 v0 = xp[0], v1 = xp[1];
            xsf[mt][0] = v0.x; xsf[mt][1] = v0.y; xsf[mt][2] = v0.z; xsf[mt][3] = v0.w;
            xsf[mt][4] = v1.x; xsf[mt][5] = v1.y; xsf[mt][6] = v1.z; xsf[mt][7] = v1.w;
        } else {
            #pragma unroll
            for (int j = 0; j < 8; ++j) xsf[mt][j] = 0.f;
        }
    }

    f32x4 acc[4][2];
    #pragma unroll
    for (int mt = 0; mt < 4; ++mt)
        #pragma unroll
        for (int nt = 0; nt < 2; ++nt) acc[mt][nt] = (f32x4){0.f,0.f,0.f,0.f};

    // per-lane B base pointers (row-major w3s, 16B-aligned fragments)
    const unsigned short* bb0 = w3s + (long)lr * K_TOT + kg * 8;
    const unsigned short* bb1 = bb0 + 16L * K_TOT;

    __syncthreads();   // h2s ready; no more barriers

    // ---------------- K loop: 16 chunks x 8 ksteps + b3 step -----------------
    #pragma unroll 1
    for (int c = 0; c < 16; ++c) {
        // h2 for 8 ksteps, 4 m-tiles (swizzled ds_read_b128, 4-lane broadcast)
        s16x8 h2v[4];
        #pragma unroll
        for (int mt = 0; mt < 4; ++mt) {
            const int row = w * 64 + mt * 16 + lr;
            const int boff = (row * 256 + c * 16) ^ ((row & 7) << 4);
            h2v[mt] = *(const s16x8*)((const char*)h2s + boff);
        }
        #pragma unroll
        for (int kk = 0; kk < 8; ++kk) {
            const int ks = c * 8 + kk;
            s16x8 bfrag0 = *(const s16x8*)(bb0 + ks * 32);
            s16x8 bfrag1 = *(const s16x8*)(bb1 + ks * 32);
            #pragma unroll
            for (int mt = 0; mt < 4; ++mt) {
                const float hf = bf2f((unsigned short)h2v[mt][kk]);
                ABu af;
                #pragma unroll
                for (int j = 0; j < 4; ++j)
                    af.u[j] = cvt_pk_bf16(hf * xsf[mt][2*j], hf * xsf[mt][2*j+1]);
                acc[mt][0] = __builtin_amdgcn_mfma_f32_16x16x32_bf16(af.s, bfrag0, acc[mt][0], 0,0,0);
                acc[mt][1] = __builtin_amdgcn_mfma_f32_16x16x32_bf16(af.s, bfrag1, acc[mt][1], 0,0,0);
            }
        }
    }
    {   // b3 k-step (ks = 128): A = bf16(xs)
        s16x8 bfrag0 = *(const s16x8*)(bb0 + 128 * 32);
        s16x8 bfrag1 = *(const s16x8*)(bb1 + 128 * 32);
        #pragma unroll
        for (int mt = 0; mt < 4; ++mt) {
            ABu af;
            #pragma unroll
            for (int j = 0; j < 4; ++j)
                af.u[j] = cvt_pk_bf16(xsf[mt][2*j], xsf[mt][2*j+1]);
            acc[mt][0] = __builtin_amdgcn_mfma_f32_16x16x32_bf16(af.s, bfrag0, acc[mt][0], 0,0,0);
            acc[mt][1] = __builtin_amdgcn_mfma_f32_16x16x32_bf16(af.s, bfrag1, acc[mt][1], 0,0,0);
        }
    }

    // ---------------- epilogue: atomic scatter -------------------------------
    // C layout: col = lane&15 (o), row = (lane>>4)*4 + reg (edge)
    #pragma unroll
    for (int mt = 0; mt < 4; ++mt) {
        #pragma unroll
        for (int r = 0; r < 4; ++r) {
            const int e2 = tile + w * 64 + mt * 16 + kg * 4 + r;
            if (e2 < N_EDGES) {
                const int d = dst[e2];
                atomicAdd(&agg[(long)d * F_OUT + lr],      acc[mt][0][r]);
                atomicAdd(&agg[(long)d * F_OUT + 16 + lr], acc[mt][1][r]);
            }
        }
    }
}

__global__ __launch_bounds__(256) void ecc_finalize(
    const float* __restrict__ agg, const float* __restrict__ deg,
    float* __restrict__ out)
{
    const int i = blockIdx.x * 256 + threadIdx.x;
    if (i >= N_NODES * F_OUT) return;
    const int n = i >> 5;
    const float d = fmaxf(deg[n], 1.f);
    out[i] = fmaxf(agg[i] / d, 0.f);
}

extern "C" void kernel_launch(void* const* d_in, const int* in_sizes, int n_in,
                              void* d_out, int out_size, void* d_ws, size_t ws_size,
                              hipStream_t stream) {
    const float* x   = (const float*)d_in[0];
    const float* ea  = (const float*)d_in[1];
    const float* W1  = (const float*)d_in[2];
    const float* b1  = (const float*)d_in[3];
    const float* W2  = (const float*)d_in[4];
    const float* b2  = (const float*)d_in[5];
    const float* W3  = (const float*)d_in[6];
    const float* b3  = (const float*)d_in[7];
    const int*   src = (const int*)d_in[8];
    const int*   dst = (const int*)d_in[9];
    float* out = (float*)d_out;

    float* agg = (float*)d_ws;                                // [N_NODES, F_OUT]
    float* deg = agg + (long)N_NODES * F_OUT;                 // [N_NODES]
    unsigned short* w3s = (unsigned short*)(deg + N_NODES);   // [W3S_USHORTS]

    const int nz = N_NODES * F_OUT + N_NODES;
    ecc_zero<<<(nz + 255) / 256, 256, 0, stream>>>((float*)d_ws, nz);
    ecc_w3s<<<(W3S_USHORTS + 255) / 256, 256, 0, stream>>>(W3, b3, w3s);
    ecc_main<<<NBLK, 256, 0, stream>>>(x, ea, W1, b1, W2, b2, w3s, src, dst, agg, deg);
    const int n2 = (N_NODES * F_OUT + 255) / 256;
    ecc_finalize<<<n2, 256, 0, stream>>>(agg, deg, out);
}

// Round 6
// 181.950 us; speedup vs baseline: 10.0329x; 1.2756x over previous
//
#include <hip/hip_runtime.h>

#define N_NODES 25000
#define N_EDGES 250000
#define F_IN 32
#define F_OUT 32
#define ED 6
#define H1 64
#define H2 128
#define NBLK 977                 // ceil(250000/256)
#define K_TOT 4160               // ushorts per o-row: 4096 (h2*xs) + 32 (b3) + 32 pad
#define W3S_USHORTS (32*K_TOT)   // 133120 = 266KB, L2-resident
#define W2S_USHORTS (H2*H1)      // 8192 = 16KB, L2-resident

typedef float f32x4 __attribute__((ext_vector_type(4)));
typedef short s16x8 __attribute__((ext_vector_type(8)));
typedef unsigned int u32x4 __attribute__((ext_vector_type(4)));
typedef unsigned int u32x2 __attribute__((ext_vector_type(2)));

union ABu { u32x4 u; s16x8 s; };

// HW packed f32->bf16 (RNE): S0 -> low ushort, S1 -> high ushort.
__device__ __forceinline__ unsigned cvt_pk_bf16(float lo, float hi) {
    unsigned r;
    asm("v_cvt_pk_bf16_f32 %0, %1, %2" : "=v"(r) : "v"(lo), "v"(hi));
    return r;
}
__device__ __forceinline__ unsigned short f2bf(float f) {   // init kernels only
    union { float f; unsigned u; } v; v.f = f;
    return (unsigned short)((v.u + 0x7FFF + ((v.u >> 16) & 1)) >> 16);
}
__device__ __forceinline__ float bf2f(unsigned short h) {
    union { unsigned u; float f; } v; v.u = ((unsigned)h) << 16;
    return v.f;
}

__global__ __launch_bounds__(256) void ecc_zero(float* __restrict__ ws, int n) {
    int i = blockIdx.x * 256 + threadIdx.x;
    if (i < n) ws[i] = 0.f;
}

// W3 (+b3) -> bf16 B matrix, row-major [o=32][kp=K_TOT].
__global__ __launch_bounds__(256) void ecc_w3s(
    const float* __restrict__ W3, const float* __restrict__ b3,
    unsigned short* __restrict__ w3s)
{
    int idx = blockIdx.x * 256 + threadIdx.x;
    if (idx >= W3S_USHORTS) return;
    int o = idx / K_TOT, kp = idx % K_TOT;
    float v = 0.f;
    if (kp < 4096)      { int k = kp >> 5, i = kp & 31; v = W3[(o * 32 + i) * 128 + k]; }
    else if (kp < 4128) { v = b3[o * 32 + (kp - 4096)]; }
    w3s[idx] = f2bf(v);
}

// W2 -> bf16 [o=128][c=64] row-major (same layout as input, just cast).
__global__ __launch_bounds__(256) void ecc_w2s(
    const float* __restrict__ W2, unsigned short* __restrict__ w2s)
{
    int idx = blockIdx.x * 256 + threadIdx.x;
    if (idx < W2S_USHORTS) w2s[idx] = f2bf(W2[idx]);
}

// Fused: L1 on VALU -> h1 (LDS bf16, wave-private) -> L2 via MFMA (W2 bf16
// from L2) -> h2 tile in LDS -> barrier-light MFMA K-loop (B from L2-resident
// w3s, A built on the fly via v_cvt_pk_bf16_f32) -> atomic scatter.
__global__ __launch_bounds__(256, 2) void ecc_main(
    const float* __restrict__ x,   const float* __restrict__ ea,
    const float* __restrict__ W1,  const float* __restrict__ b1,
    const unsigned short* __restrict__ w2s, const float* __restrict__ b2,
    const unsigned short* __restrict__ w3s,
    const int* __restrict__ src,   const int* __restrict__ dst,
    float* __restrict__ agg, float* __restrict__ deg)
{
    // 64KB. First 32KB doubles as h1s [e][64] bf16 (rows 128B) during phase 0;
    // then the whole thing is h2s [e][128] bf16 (rows 256B). Both XOR-swizzled
    // with ((row&7)<<4). All reads/writes are wave-private (own 64 edge rows).
    __shared__ unsigned short sm[256 * H2];

    const int t = threadIdx.x;
    const int tile = blockIdx.x * 256;
    const int e = tile + t;
    const bool ev = (e < N_EDGES);

    if (ev) atomicAdd(&deg[dst[e]], 1.f);

    const int w  = t >> 6;        // wave: owns edge rows w*64 .. w*64+63
    const int l  = t & 63;
    const int lr = l & 15;        // A-row / B-col / C-col
    const int kg = l >> 4;        // 8-wide k-group

    // ---------------- phase 0a: L1 on VALU -> h1s (bf16, swizzled) ----------
    {
        float a[ED];
        #pragma unroll
        for (int c = 0; c < ED; ++c) a[c] = ev ? ea[(long)e * ED + c] : 0.f;

        float h1[H1];
        #pragma unroll
        for (int o = 0; o < H1; ++o) {
            float acc = b1[o];
            #pragma unroll
            for (int c = 0; c < ED; ++c) acc = fmaf(W1[o * ED + c], a[c], acc);
            h1[o] = fmaxf(acc, 0.f);
        }
        #pragma unroll
        for (int q = 0; q < 8; ++q) {
            u32x4 pk;
            #pragma unroll
            for (int j = 0; j < 4; ++j)
                pk[j] = cvt_pk_bf16(h1[q*8 + 2*j], h1[q*8 + 2*j + 1]);
            const int boff = (t * 128 + q * 16) ^ ((t & 7) << 4);
            *(u32x4*)((char*)sm + boff) = pk;
        }
    }

    // ---------------- per-lane xs gather (issue early, used in K-loop) ------
    float xsf[4][8];
    #pragma unroll
    for (int mt = 0; mt < 4; ++mt) {
        const int er = tile + w * 64 + mt * 16 + lr;
        if (er < N_EDGES) {
            const float4* xp = (const float4*)(x + (long)src[er] * F_IN + kg * 8);
            float4 v0 = xp[0], v1 = xp[1];
            xsf[mt][0] = v0.x; xsf[mt][1] = v0.y; xsf[mt][2] = v0.z; xsf[mt][3] = v0.w;
            xsf[mt][4] = v1.x; xsf[mt][5] = v1.y; xsf[mt][6] = v1.z; xsf[mt][7] = v1.w;
        } else {
            #pragma unroll
            for (int j = 0; j < 8; ++j) xsf[mt][j] = 0.f;
        }
    }

    __syncthreads();

    // ---------------- phase 0b: L2 via MFMA ----------------------------------
    // C2[row=o][col=e] = sum_c W2[o][c]*h1[e][c]; A=w2s rows, B=h1s rows.
    {
        // hoist this wave's h1 B-fragments (then h1s region is dead)
        s16x8 hb[4][2];
        #pragma unroll
        for (int ne = 0; ne < 4; ++ne) {
            const int er = w * 64 + ne * 16 + lr;
            #pragma unroll
            for (int ks = 0; ks < 2; ++ks) {
                const int boff = (er * 128 + ks * 64 + kg * 16) ^ ((er & 7) << 4);
                hb[ne][ks] = *(const s16x8*)((const char*)sm + boff);
            }
        }
        __syncthreads();   // all h1 reads done before h2 overwrites region

        #pragma unroll
        for (int mo = 0; mo < 8; ++mo) {
            s16x8 a2[2];
            #pragma unroll
            for (int ks = 0; ks < 2; ++ks)
                a2[ks] = *(const s16x8*)(w2s + (mo*16 + lr) * 64 + ks*32 + kg*8);
            const float4 bv = *(const float4*)(b2 + mo*16 + kg*4);
            #pragma unroll
            for (int ne = 0; ne < 4; ++ne) {
                f32x4 c = (f32x4){0.f, 0.f, 0.f, 0.f};
                c = __builtin_amdgcn_mfma_f32_16x16x32_bf16(a2[0], hb[ne][0], c, 0,0,0);
                c = __builtin_amdgcn_mfma_f32_16x16x32_bf16(a2[1], hb[ne][1], c, 0,0,0);
                // lane: e = w*64+ne*16+lr, o = mo*16+kg*4+r (r=0..3 consecutive)
                const unsigned p0 = cvt_pk_bf16(fmaxf(c[0]+bv.x, 0.f), fmaxf(c[1]+bv.y, 0.f));
                const unsigned p1 = cvt_pk_bf16(fmaxf(c[2]+bv.z, 0.f), fmaxf(c[3]+bv.w, 0.f));
                const int er = w * 64 + ne * 16 + lr;
                const int boff = (er * 256 + (mo*16 + kg*4) * 2) ^ ((er & 7) << 4);
                *(u32x2*)((char*)sm + boff) = (u32x2){p0, p1};
            }
        }
    }

    f32x4 acc[4][2];
    #pragma unroll
    for (int mt = 0; mt < 4; ++mt)
        #pragma unroll
        for (int nt = 0; nt < 2; ++nt) acc[mt][nt] = (f32x4){0.f,0.f,0.f,0.f};

    const unsigned short* bb0 = w3s + (long)lr * K_TOT + kg * 8;
    const unsigned short* bb1 = bb0 + 16L * K_TOT;

    __syncthreads();   // h2s ready

    // ---------------- K loop: 16 chunks x 8 ksteps + b3 step -----------------
    #pragma unroll 1
    for (int c = 0; c < 16; ++c) {
        s16x8 h2v[4];
        #pragma unroll
        for (int mt = 0; mt < 4; ++mt) {
            const int row = w * 64 + mt * 16 + lr;
            const int boff = (row * 256 + c * 16) ^ ((row & 7) << 4);
            h2v[mt] = *(const s16x8*)((const char*)sm + boff);
        }
        #pragma unroll
        for (int kk = 0; kk < 8; ++kk) {
            const int ks = c * 8 + kk;
            s16x8 bfrag0 = *(const s16x8*)(bb0 + ks * 32);
            s16x8 bfrag1 = *(const s16x8*)(bb1 + ks * 32);
            #pragma unroll
            for (int mt = 0; mt < 4; ++mt) {
                const float hf = bf2f((unsigned short)h2v[mt][kk]);
                ABu af;
                #pragma unroll
                for (int j = 0; j < 4; ++j)
                    af.u[j] = cvt_pk_bf16(hf * xsf[mt][2*j], hf * xsf[mt][2*j+1]);
                acc[mt][0] = __builtin_amdgcn_mfma_f32_16x16x32_bf16(af.s, bfrag0, acc[mt][0], 0,0,0);
                acc[mt][1] = __builtin_amdgcn_mfma_f32_16x16x32_bf16(af.s, bfrag1, acc[mt][1], 0,0,0);
            }
        }
    }
    {   // b3 k-step (ks = 128): A = bf16(xs)
        s16x8 bfrag0 = *(const s16x8*)(bb0 + 128 * 32);
        s16x8 bfrag1 = *(const s16x8*)(bb1 + 128 * 32);
        #pragma unroll
        for (int mt = 0; mt < 4; ++mt) {
            ABu af;
            #pragma unroll
            for (int j = 0; j < 4; ++j)
                af.u[j] = cvt_pk_bf16(xsf[mt][2*j], xsf[mt][2*j+1]);
            acc[mt][0] = __builtin_amdgcn_mfma_f32_16x16x32_bf16(af.s, bfrag0, acc[mt][0], 0,0,0);
            acc[mt][1] = __builtin_amdgcn_mfma_f32_16x16x32_bf16(af.s, bfrag1, acc[mt][1], 0,0,0);
        }
    }

    // ---------------- epilogue: atomic scatter -------------------------------
    #pragma unroll
    for (int mt = 0; mt < 4; ++mt) {
        #pragma unroll
        for (int r = 0; r < 4; ++r) {
            const int e2 = tile + w * 64 + mt * 16 + kg * 4 + r;
            if (e2 < N_EDGES) {
                const int d = dst[e2];
                atomicAdd(&agg[(long)d * F_OUT + lr],      acc[mt][0][r]);
                atomicAdd(&agg[(long)d * F_OUT + 16 + lr], acc[mt][1][r]);
            }
        }
    }
}

__global__ __launch_bounds__(256) void ecc_finalize(
    const float* __restrict__ agg, const float* __restrict__ deg,
    float* __restrict__ out)
{
    const int i = blockIdx.x * 256 + threadIdx.x;
    if (i >= N_NODES * F_OUT) return;
    const int n = i >> 5;
    const float d = fmaxf(deg[n], 1.f);
    out[i] = fmaxf(agg[i] / d, 0.f);
}

extern "C" void kernel_launch(void* const* d_in, const int* in_sizes, int n_in,
                              void* d_out, int out_size, void* d_ws, size_t ws_size,
                              hipStream_t stream) {
    const float* x   = (const float*)d_in[0];
    const float* ea  = (const float*)d_in[1];
    const float* W1  = (const float*)d_in[2];
    const float* b1  = (const float*)d_in[3];
    const float* W2  = (const float*)d_in[4];
    const float* b2  = (const float*)d_in[5];
    const float* W3  = (const float*)d_in[6];
    const float* b3  = (const float*)d_in[7];
    const int*   src = (const int*)d_in[8];
    const int*   dst = (const int*)d_in[9];
    float* out = (float*)d_out;

    float* agg = (float*)d_ws;                                // [N_NODES, F_OUT]
    float* deg = agg + (long)N_NODES * F_OUT;                 // [N_NODES]
    unsigned short* w3s = (unsigned short*)(deg + N_NODES);   // [W3S_USHORTS]
    unsigned short* w2s = w3s + W3S_USHORTS;                  // [W2S_USHORTS]

    const int nz = N_NODES * F_OUT + N_NODES;
    ecc_zero<<<(nz + 255) / 256, 256, 0, stream>>>((float*)d_ws, nz);
    ecc_w3s<<<(W3S_USHORTS + 255) / 256, 256, 0, stream>>>(W3, b3, w3s);
    ecc_w2s<<<(W2S_USHORTS + 255) / 256, 256, 0, stream>>>(W2, w2s);
    ecc_main<<<NBLK, 256, 0, stream>>>(x, ea, W1, b1, w2s, b2, w3s, src, dst, agg, deg);
    const int n2 = (N_NODES * F_OUT + 255) / 256;
    ecc_finalize<<<n2, 256, 0, stream>>>(agg, deg, out);
}